// Round 2
// baseline (431.057 us; speedup 1.0000x reference)
//
#include <hip/hip_runtime.h>
#include <math.h>

#define HID 1024
#define NROWS 2048

typedef __attribute__((ext_vector_type(8))) short short8;
typedef __attribute__((ext_vector_type(4))) short short4_t;
typedef __attribute__((ext_vector_type(4))) float f32x4;

__device__ __forceinline__ short f2bf(float f) {
  union { float f; unsigned u; } v; v.f = f;
  unsigned r = v.u + 0x7fffu + ((v.u >> 16) & 1u);
  return (short)(r >> 16);
}
__device__ __forceinline__ float bf2f(short s) {
  union { unsigned u; float f; } v; v.u = ((unsigned)(unsigned short)s) << 16;
  return v.f;
}
__device__ __forceinline__ float wave_sum(float a) {
#pragma unroll
  for (int off = 32; off; off >>= 1) a += __shfl_xor(a, off, 64);
  return a;
}

// ---------------------------------------------------------------------------
// PREP: block 0 = classify; blocks 1..2048 = x fp32->bf16; rest = transposes
// (fp32 [K,N] -> bf16 [Npad,K]). Wl0 padded to 10240 zero rows.
// ---------------------------------------------------------------------------
__global__ __launch_bounds__(256) void prep(
    const float* __restrict__ x, const int* __restrict__ y,
    const float* __restrict__ Wp0, const float* __restrict__ Wp1,
    const float* __restrict__ Wp2, const float* __restrict__ Wl0,
    const float* __restrict__ Wl1, const float* __restrict__ Wl2,
    short* __restrict__ xb,
    int* __restrict__ counts, int* __restrict__ slot_of_row,
    int* __restrict__ rows1, int* __restrict__ rows2,
    short* __restrict__ T0, short* __restrict__ T1, short* __restrict__ T2,
    short* __restrict__ T3, short* __restrict__ T4, short* __restrict__ T5) {
  const int tid = threadIdx.x;
  int b = blockIdx.x;
  if (b == 0) {                       // ---- classify ----
    __shared__ int c1s, c2s;
    if (tid == 0) { c1s = 0; c2s = 0; }
    __syncthreads();
    for (int r = tid; r < NROWS; r += 256) {
      const int yy = y[r];
      if (yy >= 20000) {
        const int s = atomicAdd(&c2s, 1);
        slot_of_row[r] = s; rows2[s] = r;
      } else if (yy >= 10000) {
        const int s = atomicAdd(&c1s, 1);
        slot_of_row[r] = s; rows1[s] = r;
      } else {
        slot_of_row[r] = -1;
      }
    }
    __syncthreads();
    if (tid == 0) { counts[0] = NROWS; counts[1] = c1s; counts[2] = c2s; }
    return;
  }
  if (b <= 2048) {                    // ---- cvt x ----
    const int i = ((b - 1) * 256 + tid) * 4;
    short4_t o;
    o.x = f2bf(x[i + 0]); o.y = f2bf(x[i + 1]);
    o.z = f2bf(x[i + 2]); o.w = f2bf(x[i + 3]);
    *(short4_t*)&xb[i] = o;
    return;
  }
  b -= 2049;                          // ---- transposes ----
  const float* W; short* BT; int K, N, Npad, tn;
  if (b < 1024)                { W = Wp0; BT = T0; K = 1024; N = 1024;  Npad = 1024;  tn = 32;   }
  else if ((b -= 1024) < 256)  { W = Wp1; BT = T1; K = 1024; N = 256;   Npad = 256;   tn = 8;    }
  else if ((b -= 256) < 128)   { W = Wp2; BT = T2; K = 1024; N = 64;    Npad = 128;   tn = 4;    }
  else if ((b -= 128) < 10240) { W = Wl0; BT = T3; K = 1024; N = 10000; Npad = 10240; tn = 320;  }
  else if ((b -= 10240) < 7520){ W = Wl1; BT = T4; K = 256;  N = 30000; Npad = 30080; tn = 940;  }
  else { b -= 7520;              W = Wl2; BT = T5; K = 64;   N = 52000; Npad = 52096; tn = 1628; }

  __shared__ float T[32][33];
  const int n0 = (b % tn) * 32, k0 = (b / tn) * 32;
  const int r = tid >> 3, c = (tid & 7) * 4;
  float v0 = 0.f, v1 = 0.f, v2 = 0.f, v3 = 0.f;
  const float* p = &W[(size_t)(k0 + r) * N];
  if (n0 + c + 3 < N) {
    v0 = p[n0 + c]; v1 = p[n0 + c + 1]; v2 = p[n0 + c + 2]; v3 = p[n0 + c + 3];
  } else {
    if (n0 + c + 0 < N) v0 = p[n0 + c + 0];
    if (n0 + c + 1 < N) v1 = p[n0 + c + 1];
    if (n0 + c + 2 < N) v2 = p[n0 + c + 2];
  }
  T[r][c] = v0; T[r][c + 1] = v1; T[r][c + 2] = v2; T[r][c + 3] = v3;
  __syncthreads();
  const int nl = tid >> 3, kl = (tid & 7) * 4;
  const int n = n0 + nl;
  if (n < Npad) {
    short4_t o;
    o.x = (n < N) ? f2bf(T[kl + 0][nl]) : (short)0;
    o.y = (n < N) ? f2bf(T[kl + 1][nl]) : (short)0;
    o.z = (n < N) ? f2bf(T[kl + 2][nl]) : (short)0;
    o.w = (n < N) ? f2bf(T[kl + 3][nl]) : (short)0;
    *(short4_t*)&BT[(size_t)n * K + k0 + kl] = o;
  }
}

// ---------------------------------------------------------------------------
// Shared helpers for MFMA kernels.
// ---------------------------------------------------------------------------
#define GLOAD_LDS(g, l)                                                      \
  __builtin_amdgcn_global_load_lds(                                          \
      (const __attribute__((address_space(1))) void*)(g),                    \
      (__attribute__((address_space(3))) void*)(l), 16, 0, 0)

#define BARR do { asm volatile("" ::: "memory");                             \
                  __builtin_amdgcn_s_barrier();                              \
                  asm volatile("" ::: "memory"); } while (0)

// Stage 128 rows x 64 K bf16 (16 KB) from rows [row0, row0+128) with given
// row stride (in shorts). 2 gload_lds instr per wave, 8 waves cover it.
__device__ __forceinline__ void stage_half(const short* __restrict__ src,
                                           size_t row0, int kOff, short* dst,
                                           int stride, int w, int rsub, int kc) {
  const short* g0 = src + (row0 + (size_t)(w * 8 + rsub)) * (size_t)stride
                    + kOff + kc * 8;
  GLOAD_LDS(g0, dst + w * 512);
  GLOAD_LDS(g0 + (size_t)64 * stride, dst + 4096 + w * 512);
}

// Per-wave fragment reads for the 8-wave (2x4) map over a 128x128 quadrant.
// base = 128-row x 64-K LDS block (XOR-swizzled, row*64 + (slot^row&7)*8).
#define RD_A8(dst, base) do {                                                \
  _Pragma("unroll") for (int mt = 0; mt < 4; ++mt)                           \
  _Pragma("unroll") for (int kk = 0; kk < 2; ++kk)                           \
    dst[mt * 2 + kk] = *(const short8*)((base) +                             \
        (pm * 64 + mt * 16 + ln) * 64 + (((kk * 4 + quad) ^ l7) << 3));      \
} while (0)

#define RD_B4(dst, base) do {                                                \
  _Pragma("unroll") for (int nt = 0; nt < 2; ++nt)                           \
  _Pragma("unroll") for (int kk = 0; kk < 2; ++kk)                           \
    dst[nt * 2 + kk] = *(const short8*)((base) +                             \
        (pn * 32 + nt * 16 + ln) * 64 + (((kk * 4 + quad) ^ l7) << 3));      \
} while (0)

#define MFMA16(ACC, ar, br) do {                                             \
  __builtin_amdgcn_s_setprio(1);                                             \
  _Pragma("unroll") for (int mt = 0; mt < 4; ++mt)                           \
  _Pragma("unroll") for (int nt = 0; nt < 2; ++nt)                           \
  _Pragma("unroll") for (int kk = 0; kk < 2; ++kk)                           \
    ACC[mt][nt] = __builtin_amdgcn_mfma_f32_16x16x32_bf16(                   \
        ar[mt * 2 + kk], br[nt * 2 + kk], ACC[mt][nt], 0, 0, 0);             \
  __builtin_amdgcn_s_setprio(0);                                             \
} while (0)

// ---------------------------------------------------------------------------
// 128x128-tile MFMA main loop (4-wave) — used by proj_all only.
// ---------------------------------------------------------------------------
__device__ __forceinline__ void mfma_mainloop(const short* aB[4], const short* bB[4],
                                              short* As, short* Bs,
                                              f32x4 acc[4][4],
                                              int K, int w, int lane) {
  const int quad = lane >> 4, ln = lane & 15;
  const int wm = w >> 1, wn = w & 1;
  const int l7 = ln & 7;
  for (int kt = 0; kt < K; kt += 64) {
#pragma unroll
    for (int i = 0; i < 4; ++i) {
      const int row = w * 32 + i * 8;
      __builtin_amdgcn_global_load_lds(
          (const __attribute__((address_space(1))) void*)(aB[i] + kt),
          (__attribute__((address_space(3))) void*)(As + row * 64), 16, 0, 0);
      __builtin_amdgcn_global_load_lds(
          (const __attribute__((address_space(1))) void*)(bB[i] + kt),
          (__attribute__((address_space(3))) void*)(Bs + row * 64), 16, 0, 0);
    }
    __syncthreads();
#pragma unroll
    for (int ks = 0; ks < 2; ++ks) {
      const int kcs = ks * 4 + quad;
      short8 af[4], bfr[4];
#pragma unroll
      for (int mt = 0; mt < 4; ++mt) {
        const int row = wm * 64 + mt * 16 + ln;
        af[mt] = *(const short8*)(As + ((row * 8 + (kcs ^ l7)) << 3));
      }
#pragma unroll
      for (int nt = 0; nt < 4; ++nt) {
        const int rowb = wn * 64 + nt * 16 + ln;
        bfr[nt] = *(const short8*)(Bs + ((rowb * 8 + (kcs ^ l7)) << 3));
      }
#pragma unroll
      for (int mt = 0; mt < 4; ++mt)
#pragma unroll
        for (int nt = 0; nt < 4; ++nt)
          acc[mt][nt] = __builtin_amdgcn_mfma_f32_16x16x32_bf16(
              af[mt], bfr[nt], acc[mt][nt], 0, 0, 0);
    }
    __syncthreads();
  }
}

// C/D layout: col = lane&15, row = (lane>>4)*4 + reg   [verified m89/m91]

// ---------------------------------------------------------------------------
// PROJ_ALL (176 blocks, 256 thr): head proj + tail projs on compacted rows.
// ---------------------------------------------------------------------------
__global__ __launch_bounds__(256) void proj_all(
    const short* __restrict__ xb,
    const short* __restrict__ WpT0, const short* __restrict__ WpT1,
    const short* __restrict__ WpT2,
    short* __restrict__ P0b, short* __restrict__ P1c, short* __restrict__ P2c,
    const int* __restrict__ rows1, const int* __restrict__ rows2,
    const int* __restrict__ counts) {
  int b = blockIdx.x;
  const short* BT; short* C; int N, r0, c0, cnt;
  const int* rowlist = nullptr;
  if (b < 128) {
    BT = WpT0; C = P0b; N = 1024;
    c0 = (b & 7) * 128; r0 = (b >> 3) * 128; cnt = NROWS;
  } else if (b < 160) {
    b -= 128; BT = WpT1; C = P1c; N = 256;
    c0 = (b & 1) * 128; r0 = (b >> 1) * 128; rowlist = rows1; cnt = counts[1];
  } else {
    b -= 160; BT = WpT2; C = P2c; N = 64;
    c0 = 0; r0 = b * 128; rowlist = rows2; cnt = counts[2];
  }
  if (r0 >= cnt) return;

  __shared__ short As[128 * 64];
  __shared__ short Bs[128 * 64];
  const int tid = threadIdx.x;
  const int w = tid >> 6, lane = tid & 63;
  const int quad = lane >> 4, ln = lane & 15;
  const int wm = w >> 1, wn = w & 1;
  const int rsub = lane >> 3;
  const int kc = (lane & 7) ^ rsub;
  const int K = 1024;

  const short* aB[4]; const short* bB[4];
#pragma unroll
  for (int i = 0; i < 4; ++i) {
    const int sl = r0 + w * 32 + i * 8 + rsub;
    const int ar = rowlist ? rowlist[sl < cnt ? sl : cnt - 1] : sl;
    aB[i] = xb + (size_t)ar * K + kc * 8;
    bB[i] = BT + (size_t)(c0 + w * 32 + i * 8 + rsub) * K + kc * 8;
  }

  f32x4 acc[4][4];
  const f32x4 zero = {0.f, 0.f, 0.f, 0.f};
#pragma unroll
  for (int i = 0; i < 4; ++i)
#pragma unroll
    for (int j = 0; j < 4; ++j) acc[i][j] = zero;
  mfma_mainloop(aB, bB, As, Bs, acc, K, w, lane);
#pragma unroll
  for (int mt = 0; mt < 4; ++mt)
#pragma unroll
    for (int r = 0; r < 4; ++r) {
      const int grow = r0 + wm * 64 + mt * 16 + quad * 4 + r;
#pragma unroll
      for (int nt = 0; nt < 4; ++nt) {
        const int cg = c0 + wn * 64 + nt * 16 + ln;
        if (cg < N) C[(size_t)grow * N + cg] = f2bf(acc[mt][nt][r]);
      }
    }
}

// ---------------------------------------------------------------------------
// LOGIT_FUSED (1216 blocks x 512 thr): head (blocks 0..319) + tail1
// (320..799) + tail2 (800..1215) in ONE launch so the tails fill the CUs
// left idle by the head's 320-on-256 second round.
//
// Head: 256x256 tile, BK=64, graded 4-phase schedule, everything staged
// 2 K-tiles ahead, ONE vmcnt(8) per tile (>=5-phase slack on every load),
// 4 barriers/tile, operand-register reuse (24 LDS reads/tile).
//   ph1 (qa0,qb0): rd aq0(8)+bq0(4)            [bq0 kept to ph4, aq0 to ph2]
//   ph2 (qa0,qb1): issue A0,B0(u+2); rd bq1(4)
//   ph3 (qa1,qb1): issue B1(u+2);    rd aq1(8)
//   ph4 (qa1,qb0): issue A1(u+2);    no reads, no trailing barrier
// Region safety: each stage targets a region whose last LDS-read was in the
// previous phase (barrier-separated). vmcnt(8) at ph1 leaves exactly tile
// u+1's 8 loads in flight; last tile uses vmcnt(0).
//
// Tails: persistent blocks, A staged once, loop over col-splits.
//   tail1 (K=256): 8 cs/block, single-buffered B (A 64K + B 64K LDS).
//   tail2 (K=64): 16 cs/block, double-buffered B, counted vmcnt(2).
// ---------------------------------------------------------------------------
__global__ __launch_bounds__(512, 2) void logit_fused(
    const short* __restrict__ P0b, const short* __restrict__ WlT0,
    const float* __restrict__ bl0, float* __restrict__ psh,
    const short* __restrict__ P1c, const short* __restrict__ WlT1,
    const float* __restrict__ bl1, float* __restrict__ ps1,
    const short* __restrict__ P2c, const short* __restrict__ WlT2,
    const float* __restrict__ bl2, float* __restrict__ ps2,
    const int* __restrict__ counts) {
  __shared__ short lds[65536];         // 128 KiB staging
  __shared__ float psE[4][2][256];     // cross-wave exp-sum partials (8 KiB)
  const int tid = threadIdx.x;
  const int w = tid >> 6, lane = tid & 63;
  const int quad = lane >> 4, ln = lane & 15, l7 = lane & 7;
  const int pm = w >> 2, pn = w & 3;
  const int rsub = lane >> 3, kc = (lane & 7) ^ rsub;
  const int b = blockIdx.x;

  if (b < 320) {
    // ------------------------------ HEAD ------------------------------
    const int xcd = b & 7, j = b >> 3;
    const int cb = xcd * 5 + j % 5, rb = j / 5;    // 5 col-tiles/XCD
    const int r0 = rb * 256;
    const size_t c0 = (size_t)cb * 256;
    short* const Abase = lds;
    short* const Bbase = lds + 32768;

    // prologue: tile0 then tile1 (8 stage_half = 16 vmem instr)
    stage_half(P0b, (size_t)r0,        0,  Abase,          1024, w, rsub, kc);
    stage_half(P0b, (size_t)r0 + 128,  0,  Abase + 8192,   1024, w, rsub, kc);
    stage_half(WlT0, c0,               0,  Bbase,          1024, w, rsub, kc);
    stage_half(WlT0, c0 + 128,         0,  Bbase + 8192,   1024, w, rsub, kc);
    stage_half(P0b, (size_t)r0,        64, Abase + 16384,  1024, w, rsub, kc);
    stage_half(P0b, (size_t)r0 + 128,  64, Abase + 24576,  1024, w, rsub, kc);
    stage_half(WlT0, c0,               64, Bbase + 16384,  1024, w, rsub, kc);
    stage_half(WlT0, c0 + 128,         64, Bbase + 24576,  1024, w, rsub, kc);

    f32x4 acc[2][2][4][2];
    const f32x4 zero = {0.f, 0.f, 0.f, 0.f};
#pragma unroll
    for (int qa = 0; qa < 2; ++qa)
#pragma unroll
      for (int qb = 0; qb < 2; ++qb)
#pragma unroll
        for (int mt = 0; mt < 4; ++mt)
#pragma unroll
          for (int nt = 0; nt < 2; ++nt) acc[qa][qb][mt][nt] = zero;

#pragma unroll 2
    for (int u = 0; u < 16; ++u) {
      const int cc = u & 1;
      short* const Ab = Abase + cc * 16384;
      short* const Bb = Bbase + cc * 16384;
      const int k2 = (u + 2) << 6;
      short8 aq0[8], aq1[8], bq0[4], bq1[4];
      // ---- ph1: quadrant (0,0) ----
      if (u < 15) { asm volatile("s_waitcnt vmcnt(8)" ::: "memory"); }
      else        { asm volatile("s_waitcnt vmcnt(0)" ::: "memory"); }
      __builtin_amdgcn_s_barrier();
      asm volatile("" ::: "memory");
      RD_A8(aq0, Ab);
      RD_B4(bq0, Bb);
      MFMA16(acc[0][0], aq0, bq0);
      BARR;
      // ---- ph2: quadrant (0,1); stage A0,B0 of u+2 ----
      if (u < 14) {
        stage_half(P0b, (size_t)r0, k2, Ab, 1024, w, rsub, kc);
        stage_half(WlT0, c0, k2, Bb, 1024, w, rsub, kc);
      }
      RD_B4(bq1, Bb + 8192);
      MFMA16(acc[0][1], aq0, bq1);
      BARR;
      // ---- ph3: quadrant (1,1); stage B1 of u+2 ----
      if (u < 14) stage_half(WlT0, c0 + 128, k2, Bb + 8192, 1024, w, rsub, kc);
      RD_A8(aq1, Ab + 8192);
      MFMA16(acc[1][1], aq1, bq1);
      BARR;
      // ---- ph4: quadrant (1,0); stage A1 of u+2; no reads/barrier ----
      if (u < 14) stage_half(P0b, (size_t)r0 + 128, k2, Ab + 8192, 1024, w, rsub, kc);
      MFMA16(acc[1][0], aq1, bq0);
    }

    // epilogue: exp-sum partials per 128-col split (nsplit = 79)
    float bv[2][2];
#pragma unroll
    for (int qb = 0; qb < 2; ++qb)
#pragma unroll
      for (int nt = 0; nt < 2; ++nt) {
        const size_t cg = c0 + qb * 128 + pn * 32 + nt * 16 + ln;
        bv[qb][nt] = (cg < 10000) ? bl0[cg] : -1.0e30f;  // pad -> exp 0
      }
#pragma unroll
    for (int qa = 0; qa < 2; ++qa)
#pragma unroll
      for (int qb = 0; qb < 2; ++qb)
#pragma unroll
        for (int mt = 0; mt < 4; ++mt)
#pragma unroll
          for (int r = 0; r < 4; ++r) {
            float s = __expf(acc[qa][qb][mt][0][r] + bv[qb][0]) +
                      __expf(acc[qa][qb][mt][1][r] + bv[qb][1]);
#pragma unroll
            for (int off = 1; off < 16; off <<= 1) s += __shfl_xor(s, off, 64);
            if (ln == 0)
              psE[pn][qb][qa * 128 + pm * 64 + mt * 16 + quad * 4 + r] = s;
          }
    BARR;
    {
      const int qb = tid >> 8, row = tid & 255;
      const int cs = cb * 2 + qb;
      if (cs < 79)
        psh[(size_t)(r0 + row) * 79 + cs] =
            psE[0][qb][row] + psE[1][qb][row] + psE[2][qb][row] + psE[3][qb][row];
    }
    return;
  }

  if (b < 800) {
    // ------------------------------ TAIL 1 ------------------------------
    const int b1 = b - 320;
    const int grp = b1 >> 4, rb = b1 & 15;     // 30 groups x 16 rb
    const int r0 = rb * 128;
    if (r0 >= counts[1]) return;
    const int cs0 = grp * 8;
    short* const As = lds;                     // [4 kt][128][64]  64 KB
    short* const Bs = lds + 32768;             // [4 kt][128][64]  64 KB
#pragma unroll
    for (int kt = 0; kt < 4; ++kt)
      stage_half(P1c, (size_t)r0, kt * 64, As + kt * 8192, 256, w, rsub, kc);
    for (int g = 0; g < 8; ++g) {
      const int cs = cs0 + g;
      if (cs >= 235) break;
#pragma unroll
      for (int kt = 0; kt < 4; ++kt)
        stage_half(WlT1, (size_t)cs * 128, kt * 64, Bs + kt * 8192, 256, w, rsub, kc);
      asm volatile("s_waitcnt vmcnt(0)" ::: "memory");
      __builtin_amdgcn_s_barrier();
      asm volatile("" ::: "memory");
      f32x4 acc[4][2];
      const f32x4 zero = {0.f, 0.f, 0.f, 0.f};
#pragma unroll
      for (int mt = 0; mt < 4; ++mt)
#pragma unroll
        for (int nt = 0; nt < 2; ++nt) acc[mt][nt] = zero;
#pragma unroll
      for (int kt = 0; kt < 4; ++kt) {
        short8 a_[8], b_[4];
        RD_A8(a_, As + kt * 8192);
        RD_B4(b_, Bs + kt * 8192);
        MFMA16(acc, a_, b_);
      }
      float bv[2];
#pragma unroll
      for (int nt = 0; nt < 2; ++nt) {
        const int cg = cs * 128 + pn * 32 + nt * 16 + ln;
        bv[nt] = (cg < 30000) ? bl1[cg] : -1.0e30f;
      }
#pragma unroll
      for (int mt = 0; mt < 4; ++mt)
#pragma unroll
        for (int r = 0; r < 4; ++r) {
          float s = __expf(acc[mt][0][r] + bv[0]) + __expf(acc[mt][1][r] + bv[1]);
#pragma unroll
          for (int off = 1; off < 16; off <<= 1) s += __shfl_xor(s, off, 64);
          if (ln == 0) psE[pn][0][pm * 64 + mt * 16 + quad * 4 + r] = s;
        }
      BARR;   // all B-reads + psE writes done
      if (tid < 128)
        ps1[(size_t)(r0 + tid) * 235 + cs] =
            psE[0][0][tid] + psE[1][0][tid] + psE[2][0][tid] + psE[3][0][tid];
      // next iteration's vmcnt(0)+barrier orders psE rewrite after this read
    }
    return;
  }

  // ------------------------------ TAIL 2 ------------------------------
  {
    const int b2 = b - 800;
    const int grp = b2 >> 4, rb = b2 & 15;     // 26 groups x 16 rb
    const int r0 = rb * 128;
    if (r0 >= counts[2]) return;
    const int cs0 = grp * 16;
    short* const As = lds;                     // 16 KB
    short* const Bbuf0 = lds + 8192;           // 16 KB
    short* const Bbuf1 = lds + 16384;          // 16 KB
    stage_half(P2c, (size_t)r0, 0, As, 64, w, rsub, kc);
    stage_half(WlT2, (size_t)cs0 * 128, 0, Bbuf0, 64, w, rsub, kc);
    for (int g = 0; g < 16; ++g) {
      const int cs = cs0 + g;
      if (cs >= 407) break;
      const bool more = (g < 15) && (cs + 1 < 407);
      if (more)
        stage_half(WlT2, (size_t)(cs + 1) * 128, 0, (g & 1) ? Bbuf0 : Bbuf1,
                   64, w, rsub, kc);
      if (more) { asm volatile("s_waitcnt vmcnt(2)" ::: "memory"); }
      else      { asm volatile("s_waitcnt vmcnt(0)" ::: "memory"); }
      __builtin_amdgcn_s_barrier();
      asm volatile("" ::: "memory");
      short8 a_[8], b_[4];
      RD_A8(a_, As);
      RD_B4(b_, (g & 1) ? Bbuf1 : Bbuf0);
      f32x4 acc[4][2];
      const f32x4 zero = {0.f, 0.f, 0.f, 0.f};
#pragma unroll
      for (int mt = 0; mt < 4; ++mt)
#pragma unroll
        for (int nt = 0; nt < 2; ++nt) acc[mt][nt] = zero;
      MFMA16(acc, a_, b_);
      float bv[2];
#pragma unroll
      for (int nt = 0; nt < 2; ++nt) {
        const int cg = cs * 128 + pn * 32 + nt * 16 + ln;
        bv[nt] = (cg < 52000) ? bl2[cg] : -1.0e30f;
      }
#pragma unroll
      for (int mt = 0; mt < 4; ++mt)
#pragma unroll
        for (int r = 0; r < 4; ++r) {
          float s = __expf(acc[mt][0][r] + bv[0]) + __expf(acc[mt][1][r] + bv[1]);
#pragma unroll
          for (int off = 1; off < 16; off <<= 1) s += __shfl_xor(s, off, 64);
          if (ln == 0) psE[pn][0][pm * 64 + mt * 16 + quad * 4 + r] = s;
        }
      BARR;
      if (tid < 128)
        ps2[(size_t)(r0 + tid) * 407 + cs] =
            psE[0][0][tid] + psE[1][0][tid] + psE[2][0][tid] + psE[3][0][tid];
    }
    return;
  }
}

// ---------------------------------------------------------------------------
// FINALIZE: one wave per row (unchanged).
// ---------------------------------------------------------------------------
__global__ __launch_bounds__(256) void finalize(
    const short* __restrict__ P0b, const short* __restrict__ P1c,
    const short* __restrict__ P2c,
    const short* __restrict__ WlT0, const float* __restrict__ bl0,
    const short* __restrict__ WlT1, const float* __restrict__ bl1,
    const short* __restrict__ WlT2, const float* __restrict__ bl2,
    const float* __restrict__ Wc, const float* __restrict__ bc,
    const int* __restrict__ y, const int* __restrict__ slot_of_row,
    const float* __restrict__ psh, const float* __restrict__ ps1,
    const float* __restrict__ ps2, float* __restrict__ out) {
  const int lane = threadIdx.x & 63;
  const int row = blockIdx.x * 4 + (threadIdx.x >> 6);

  float a0 = 0.f, a1 = 0.f;
  for (int k = lane; k < HID; k += 64) {
    const float p = bf2f(P0b[(size_t)row * HID + k]);
    a0 += p * Wc[2 * k];
    a1 += p * Wc[2 * k + 1];
  }
  a0 = wave_sum(a0);
  a1 = wave_sum(a1);
  const float cl0 = a0 + bc[0], cl1 = a1 + bc[1];

  float S = 0.f;
  for (int i = lane; i < 79; i += 64) S += psh[(size_t)row * 79 + i];
  S = wave_sum(S) + __expf(cl0) + __expf(cl1);
  const float lse = logf(S);

  const int yy = y[row];
  float nll;
  if (yy < 10000) {
    const short* pr = P0b + (size_t)row * 1024;
    const short* wr = WlT0 + (size_t)yy * 1024;
    float a = 0.f;
    for (int kk = lane * 4; kk < 1024; kk += 256) {
      const short4_t p = *(const short4_t*)(pr + kk);
      const short4_t wv = *(const short4_t*)(wr + kk);
      a += bf2f(p.x) * bf2f(wv.x) + bf2f(p.y) * bf2f(wv.y)
         + bf2f(p.z) * bf2f(wv.z) + bf2f(p.w) * bf2f(wv.w);
    }
    a = wave_sum(a);
    nll = -((a + bl0[yy]) - lse);
  } else if (yy < 20000) {
    const int t = yy - 10000;
    const int slot = slot_of_row[row];
    float S1 = 0.f;
    for (int i = lane; i < 235; i += 64) S1 += ps1[(size_t)slot * 235 + i];
    S1 = wave_sum(S1);
    const short* pr = P1c + (size_t)slot * 256;
    const short* wr = WlT1 + (size_t)t * 256;
    const int kk = lane * 4;
    const short4_t p = *(const short4_t*)(pr + kk);
    const short4_t wv = *(const short4_t*)(wr + kk);
    float a = bf2f(p.x) * bf2f(wv.x) + bf2f(p.y) * bf2f(wv.y)
            + bf2f(p.z) * bf2f(wv.z) + bf2f(p.w) * bf2f(wv.w);
    a = wave_sum(a);
    nll = -((cl1 - lse) + ((a + bl1[t]) - logf(S1)));
  } else {
    const int t = yy - 20000;
    const int slot = slot_of_row[row];
    float S2 = 0.f;
    for (int i = lane; i < 407; i += 64) S2 += ps2[(size_t)slot * 407 + i];
    S2 = wave_sum(S2);
    float a = 0.f;
    if (lane < 16) {
      const short* pr = P2c + (size_t)slot * 64;
      const short* wr = WlT2 + (size_t)t * 64;
      const int kk = lane * 4;
      const short4_t p = *(const short4_t*)(pr + kk);
      const short4_t wv = *(const short4_t*)(wr + kk);
      a = bf2f(p.x) * bf2f(wv.x) + bf2f(p.y) * bf2f(wv.y)
        + bf2f(p.z) * bf2f(wv.z) + bf2f(p.w) * bf2f(wv.w);
    }
    a = wave_sum(a);
    nll = -((cl0 - lse) + ((a + bl2[t]) - logf(S2)));
  }
  if (lane == 0) out[row] = nll;
}

// ---------------------------------------------------------------------------
extern "C" void kernel_launch(void* const* d_in, const int* in_sizes, int n_in,
                              void* d_out, int out_size, void* d_ws, size_t ws_size,
                              hipStream_t stream) {
  const float* x   = (const float*)d_in[0];
  const int*   y   = (const int*)d_in[1];
  const float* Wp0 = (const float*)d_in[2];
  const float* Wp1 = (const float*)d_in[3];
  const float* Wp2 = (const float*)d_in[4];
  const float* Wl0 = (const float*)d_in[5];
  const float* bl0 = (const float*)d_in[6];
  const float* Wl1 = (const float*)d_in[7];
  const float* bl1 = (const float*)d_in[8];
  const float* Wl2 = (const float*)d_in[9];
  const float* bl2 = (const float*)d_in[10];
  const float* Wc  = (const float*)d_in[11];
  const float* bc  = (const float*)d_in[12];
  float* out = (float*)d_out;

  float* fws = (float*)d_ws;
  float* psh = fws; fws += (size_t)NROWS * 79;
  float* ps1 = fws; fws += (size_t)NROWS * 235;
  float* ps2 = fws; fws += (size_t)NROWS * 407;
  int* iws = (int*)fws;
  int* counts      = iws; iws += 4;
  int* slot_of_row = iws; iws += NROWS;
  int* rows1       = iws; iws += NROWS;
  int* rows2       = iws; iws += NROWS;
  short* sp = (short*)iws;
  short* xb   = sp; sp += (size_t)NROWS * 1024;
  short* P0b  = sp; sp += (size_t)NROWS * 1024;
  short* P1c  = sp; sp += (size_t)NROWS * 256;
  short* P2c  = sp; sp += (size_t)NROWS * 64;
  short* WpT0 = sp; sp += (size_t)1024 * 1024;
  short* WpT1 = sp; sp += (size_t)256 * 1024;
  short* WpT2 = sp; sp += (size_t)128 * 1024;
  short* WlT0 = sp; sp += (size_t)10240 * 1024;
  short* WlT1 = sp; sp += (size_t)30080 * 256;
  short* WlT2 = sp; sp += (size_t)52096 * 64;

  dim3 blk(256);
  prep<<<dim3(24473), blk, 0, stream>>>(x, y, Wp0, Wp1, Wp2, Wl0, Wl1, Wl2,
                                        xb, counts, slot_of_row, rows1, rows2,
                                        WpT0, WpT1, WpT2, WlT0, WlT1, WlT2);
  proj_all<<<dim3(176), blk, 0, stream>>>(xb, WpT0, WpT1, WpT2, P0b, P1c, P2c,
                                          rows1, rows2, counts);
  logit_fused<<<dim3(1216), dim3(512), 0, stream>>>(
      P0b, WlT0, bl0, psh, P1c, WlT1, bl1, ps1, P2c, WlT2, bl2, ps2, counts);
  finalize<<<dim3(NROWS / 4), blk, 0, stream>>>(
      P0b, P1c, P2c, WlT0, bl0, WlT1, bl1, WlT2, bl2, Wc, bc, y, slot_of_row,
      psh, ps1, ps2, out);
}

// Round 3
// 318.273 us; speedup vs baseline: 1.3544x; 1.3544x over previous
//
#include <hip/hip_runtime.h>
#include <math.h>

#define HID 1024
#define NROWS 2048

typedef __attribute__((ext_vector_type(8))) short short8;
typedef __attribute__((ext_vector_type(4))) short short4_t;
typedef __attribute__((ext_vector_type(4))) float f32x4;

__device__ __forceinline__ short f2bf(float f) {
  union { float f; unsigned u; } v; v.f = f;
  unsigned r = v.u + 0x7fffu + ((v.u >> 16) & 1u);
  return (short)(r >> 16);
}
__device__ __forceinline__ float bf2f(short s) {
  union { unsigned u; float f; } v; v.u = ((unsigned)(unsigned short)s) << 16;
  return v.f;
}
__device__ __forceinline__ float wave_sum(float a) {
#pragma unroll
  for (int off = 32; off; off >>= 1) a += __shfl_xor(a, off, 64);
  return a;
}

// ---------------------------------------------------------------------------
// PREP: block 0 = classify; blocks 1..2048 = x fp32->bf16; rest = transposes
// (fp32 [K,N] -> bf16 [Npad,K]).  Npad now 256-multiples for the 256-wide
// logit tiles: Wl0->10240, Wl1->30208, Wl2->52224 (zero-padded rows).
// Transpose blocks: 1024+256+128+10240+7552+3264 = 22464. Grid = 24513.
// ---------------------------------------------------------------------------
__global__ __launch_bounds__(256) void prep(
    const float* __restrict__ x, const int* __restrict__ y,
    const float* __restrict__ Wp0, const float* __restrict__ Wp1,
    const float* __restrict__ Wp2, const float* __restrict__ Wl0,
    const float* __restrict__ Wl1, const float* __restrict__ Wl2,
    short* __restrict__ xb,
    int* __restrict__ counts, int* __restrict__ slot_of_row,
    int* __restrict__ rows1, int* __restrict__ rows2,
    short* __restrict__ T0, short* __restrict__ T1, short* __restrict__ T2,
    short* __restrict__ T3, short* __restrict__ T4, short* __restrict__ T5) {
  const int tid = threadIdx.x;
  int b = blockIdx.x;
  if (b == 0) {                       // ---- classify ----
    __shared__ int c1s, c2s;
    if (tid == 0) { c1s = 0; c2s = 0; }
    __syncthreads();
    for (int r = tid; r < NROWS; r += 256) {
      const int yy = y[r];
      if (yy >= 20000) {
        const int s = atomicAdd(&c2s, 1);
        slot_of_row[r] = s; rows2[s] = r;
      } else if (yy >= 10000) {
        const int s = atomicAdd(&c1s, 1);
        slot_of_row[r] = s; rows1[s] = r;
      } else {
        slot_of_row[r] = -1;
      }
    }
    __syncthreads();
    if (tid == 0) { counts[0] = NROWS; counts[1] = c1s; counts[2] = c2s; }
    return;
  }
  if (b <= 2048) {                    // ---- cvt x ----
    const int i = ((b - 1) * 256 + tid) * 4;
    short4_t o;
    o.x = f2bf(x[i + 0]); o.y = f2bf(x[i + 1]);
    o.z = f2bf(x[i + 2]); o.w = f2bf(x[i + 3]);
    *(short4_t*)&xb[i] = o;
    return;
  }
  b -= 2049;                          // ---- transposes ----
  const float* W; short* BT; int K, N, Npad, tn;
  if (b < 1024)                { W = Wp0; BT = T0; K = 1024; N = 1024;  Npad = 1024;  tn = 32;   }
  else if ((b -= 1024) < 256)  { W = Wp1; BT = T1; K = 1024; N = 256;   Npad = 256;   tn = 8;    }
  else if ((b -= 256) < 128)   { W = Wp2; BT = T2; K = 1024; N = 64;    Npad = 128;   tn = 4;    }
  else if ((b -= 128) < 10240) { W = Wl0; BT = T3; K = 1024; N = 10000; Npad = 10240; tn = 320;  }
  else if ((b -= 10240) < 7552){ W = Wl1; BT = T4; K = 256;  N = 30000; Npad = 30208; tn = 944;  }
  else { b -= 7552;              W = Wl2; BT = T5; K = 64;   N = 52000; Npad = 52224; tn = 1632; }

  __shared__ float T[32][33];
  const int n0 = (b % tn) * 32, k0 = (b / tn) * 32;
  const int r = tid >> 3, c = (tid & 7) * 4;
  float v0 = 0.f, v1 = 0.f, v2 = 0.f, v3 = 0.f;
  const float* p = &W[(size_t)(k0 + r) * N];
  if (n0 + c + 3 < N) {
    v0 = p[n0 + c]; v1 = p[n0 + c + 1]; v2 = p[n0 + c + 2]; v3 = p[n0 + c + 3];
  } else {
    if (n0 + c + 0 < N) v0 = p[n0 + c + 0];
    if (n0 + c + 1 < N) v1 = p[n0 + c + 1];
    if (n0 + c + 2 < N) v2 = p[n0 + c + 2];
  }
  T[r][c] = v0; T[r][c + 1] = v1; T[r][c + 2] = v2; T[r][c + 3] = v3;
  __syncthreads();
  const int nl = tid >> 3, kl = (tid & 7) * 4;
  const int n = n0 + nl;
  if (n < Npad) {
    short4_t o;
    o.x = (n < N) ? f2bf(T[kl + 0][nl]) : (short)0;
    o.y = (n < N) ? f2bf(T[kl + 1][nl]) : (short)0;
    o.z = (n < N) ? f2bf(T[kl + 2][nl]) : (short)0;
    o.w = (n < N) ? f2bf(T[kl + 3][nl]) : (short)0;
    *(short4_t*)&BT[(size_t)n * K + k0 + kl] = o;
  }
}

// ---------------------------------------------------------------------------
// Shared helpers.
// ---------------------------------------------------------------------------
#define GLOAD_LDS(g, l)                                                      \
  __builtin_amdgcn_global_load_lds(                                          \
      (const __attribute__((address_space(1))) void*)(g),                    \
      (__attribute__((address_space(3))) void*)(l), 16, 0, 0)

#define BARR do { asm volatile("" ::: "memory");                             \
                  __builtin_amdgcn_s_barrier();                              \
                  asm volatile("" ::: "memory"); } while (0)

#define VMW(n) asm volatile("s_waitcnt vmcnt(" #n ")" ::: "memory")

// Stage 128 rows x 64 K bf16 (16 KB); 2 gload_lds per wave, 8 waves cover it.
__device__ __forceinline__ void stage_half(const short* __restrict__ src,
                                           size_t row0, int kOff, short* dst,
                                           int stride, int w, int rsub, int kc) {
  const short* g0 = src + (row0 + (size_t)(w * 8 + rsub)) * (size_t)stride
                    + kOff + kc * 8;
  GLOAD_LDS(g0, dst + w * 512);
  GLOAD_LDS(g0 + (size_t)64 * stride, dst + 4096 + w * 512);
}

// Fragment reads for the 8-wave (2Mx4N) map over 128x128 quadrants.
#define RD_A8(dst, base) do {                                                \
  _Pragma("unroll") for (int mt = 0; mt < 4; ++mt)                           \
  _Pragma("unroll") for (int kk = 0; kk < 2; ++kk)                           \
    dst[mt * 2 + kk] = *(const short8*)((base) +                             \
        (pm * 64 + mt * 16 + ln) * 64 + (((kk * 4 + quad) ^ l7) << 3));      \
} while (0)

#define RD_B4(dst, base) do {                                                \
  _Pragma("unroll") for (int nt = 0; nt < 2; ++nt)                           \
  _Pragma("unroll") for (int kk = 0; kk < 2; ++kk)                           \
    dst[nt * 2 + kk] = *(const short8*)((base) +                             \
        (pn * 32 + nt * 16 + ln) * 64 + (((kk * 4 + quad) ^ l7) << 3));      \
} while (0)

#define MFMA16(ACC, ar, br) do {                                             \
  __builtin_amdgcn_s_setprio(1);                                             \
  _Pragma("unroll") for (int mt = 0; mt < 4; ++mt)                           \
  _Pragma("unroll") for (int nt = 0; nt < 2; ++nt)                           \
  _Pragma("unroll") for (int kk = 0; kk < 2; ++kk)                           \
    ACC[mt][nt] = __builtin_amdgcn_mfma_f32_16x16x32_bf16(                   \
        ar[mt * 2 + kk], br[nt * 2 + kk], ACC[mt][nt], 0, 0, 0);             \
  __builtin_amdgcn_s_setprio(0);                                             \
} while (0)

// ---------------------------------------------------------------------------
// 256x256 GEMM mainloop, 4 phases/K-tile, ONE barrier/phase, uniform
// >=3-phase vmcnt slack.  Issue plan (tile u, buffers c=u&1):
//   q1: wait vm(4)[A0,B0(u) land]; RD A0,B0; issue A0(u+1); MFMA(0,0)
//   q2: wait vm(4)[B1(u)];         RD B1;    issue B0(u+1); MFMA(0,1)
//   q3: wait vm(4)[A1(u)];         RD A1;    issue B1(u+1); MFMA(1,1)
//   q4: (no wait)                  regs only; issue A1(u+1); MFMA(1,0)
// Outstanding-count bookkeeping (2 loads/stage_half): steady state enters
// each phase with 8/6/6 outstanding; every wait completes exactly the two
// loads issued 3-4 phases earlier.  Last tile: q2 vm(2), q3 vm(0).
// Region overwrites are >=4 barriers after their last LDS read (bq0/aq1
// register reuse keeps q4 read-free).
// ---------------------------------------------------------------------------
__device__ __forceinline__ void gemm256(
    const short* __restrict__ A, const short* __restrict__ BT,
    int K, int NT, size_t rowA0, size_t rowB0, short* lds,
    f32x4 acc[2][2][4][2], int w, int lane) {
  const int quad = lane >> 4, ln = lane & 15, l7 = lane & 7;
  const int pm = w >> 2, pn = w & 3;
  const int rsub = lane >> 3, kc = (lane & 7) ^ rsub;
  short* const Abase = lds;
  short* const Bbase = lds + 32768;

  // prologue: tile 0, order A0,B0,B1,A1 (matches steady-state wait order)
  stage_half(A,  rowA0,       0, Abase,        K, w, rsub, kc);
  stage_half(BT, rowB0,       0, Bbase,        K, w, rsub, kc);
  stage_half(BT, rowB0 + 128, 0, Bbase + 8192, K, w, rsub, kc);
  stage_half(A,  rowA0 + 128, 0, Abase + 8192, K, w, rsub, kc);

  for (int u = 0; u < NT; ++u) {
    const int c = u & 1;
    const short* Ah = Abase + c * 16384;
    const short* Bh = Bbase + c * 16384;
    short* const An = Abase + (c ^ 1) * 16384;
    short* const Bn = Bbase + (c ^ 1) * 16384;
    const int k1 = (u + 1) << 6;
    const bool more = (u < NT - 1);
    short8 aq0[8], aq1[8], bq0[4], bq1[4];
    // ---- q1 ----
    VMW(4);
    BARR;
    RD_A8(aq0, Ah);
    RD_B4(bq0, Bh);
    if (more) stage_half(A, rowA0, k1, An, K, w, rsub, kc);
    MFMA16(acc[0][0], aq0, bq0);
    // ---- q2 ----
    if (more) { VMW(4); } else { VMW(2); }
    BARR;
    RD_B4(bq1, Bh + 8192);
    if (more) stage_half(BT, rowB0, k1, Bn, K, w, rsub, kc);
    MFMA16(acc[0][1], aq0, bq1);
    // ---- q3 ----
    if (more) { VMW(4); } else { VMW(0); }
    BARR;
    RD_A8(aq1, Ah + 8192);
    if (more) stage_half(BT, rowB0 + 128, k1, Bn + 8192, K, w, rsub, kc);
    MFMA16(acc[1][1], aq1, bq1);
    // ---- q4 (register reuse only, no barrier until next phase) ----
    BARR;
    if (more) stage_half(A, rowA0 + 128, k1, An + 8192, K, w, rsub, kc);
    MFMA16(acc[1][0], aq1, bq0);
  }
}

// C/D layout: col = lane&15, row = (lane>>4)*4 + reg   [verified m89/m91]

// Exp-sum epilogue over the 256x256 accumulator: per-row sum of
// exp(acc + bias) into two 128-col splits; write ps[row][cs].
__device__ __forceinline__ void exp_epilogue(
    f32x4 acc[2][2][4][2], const float* __restrict__ bias,
    float* __restrict__ ps, size_t c0, int Ncols, int nsplit, int r0,
    short* lds, int tid, int w, int lane) {
  const int quad = lane >> 4, ln = lane & 15;
  const int pm = w >> 2, pn = w & 3;
  float bv[2][2];
#pragma unroll
  for (int qb = 0; qb < 2; ++qb)
#pragma unroll
    for (int nt = 0; nt < 2; ++nt) {
      const size_t cg = c0 + qb * 128 + pn * 32 + nt * 16 + ln;
      bv[qb][nt] = (cg < (size_t)Ncols) ? bias[cg] : -1.0e30f;  // pad -> 0
    }
  float* const psF = (float*)lds;  // [pn][qb][256] = 8 KB (LDS reuse)
  BARR;                            // all K-loop LDS reads complete
#pragma unroll
  for (int qa = 0; qa < 2; ++qa)
#pragma unroll
    for (int qb = 0; qb < 2; ++qb)
#pragma unroll
      for (int mt = 0; mt < 4; ++mt)
#pragma unroll
        for (int r = 0; r < 4; ++r) {
          float s = __expf(acc[qa][qb][mt][0][r] + bv[qb][0]) +
                    __expf(acc[qa][qb][mt][1][r] + bv[qb][1]);
#pragma unroll
          for (int off = 1; off < 16; off <<= 1) s += __shfl_xor(s, off, 64);
          if (ln == 0)
            psF[(pn * 2 + qb) * 256 + qa * 128 + pm * 64 + mt * 16 + quad * 4 + r] = s;
        }
  BARR;
  {
    const int qb = tid >> 8, row = tid & 255;
    const int cs = (int)(c0 >> 7) + qb;
    if (cs < nsplit)
      ps[(size_t)(r0 + row) * nsplit + cs] =
          psF[(0 * 2 + qb) * 256 + row] + psF[(1 * 2 + qb) * 256 + row] +
          psF[(2 * 2 + qb) * 256 + row] + psF[(3 * 2 + qb) * 256 + row];
  }
}

// ---------------------------------------------------------------------------
// 128x128-tile MFMA main loop (4-wave) — used by proj_all only.
// ---------------------------------------------------------------------------
__device__ __forceinline__ void mfma_mainloop(const short* aB[4], const short* bB[4],
                                              short* As, short* Bs,
                                              f32x4 acc[4][4],
                                              int K, int w, int lane) {
  const int quad = lane >> 4, ln = lane & 15;
  const int wm = w >> 1, wn = w & 1;
  const int l7 = ln & 7;
  for (int kt = 0; kt < K; kt += 64) {
#pragma unroll
    for (int i = 0; i < 4; ++i) {
      const int row = w * 32 + i * 8;
      __builtin_amdgcn_global_load_lds(
          (const __attribute__((address_space(1))) void*)(aB[i] + kt),
          (__attribute__((address_space(3))) void*)(As + row * 64), 16, 0, 0);
      __builtin_amdgcn_global_load_lds(
          (const __attribute__((address_space(1))) void*)(bB[i] + kt),
          (__attribute__((address_space(3))) void*)(Bs + row * 64), 16, 0, 0);
    }
    __syncthreads();
#pragma unroll
    for (int ks = 0; ks < 2; ++ks) {
      const int kcs = ks * 4 + quad;
      short8 af[4], bfr[4];
#pragma unroll
      for (int mt = 0; mt < 4; ++mt) {
        const int row = wm * 64 + mt * 16 + ln;
        af[mt] = *(const short8*)(As + ((row * 8 + (kcs ^ l7)) << 3));
      }
#pragma unroll
      for (int nt = 0; nt < 4; ++nt) {
        const int rowb = wn * 64 + nt * 16 + ln;
        bfr[nt] = *(const short8*)(Bs + ((rowb * 8 + (kcs ^ l7)) << 3));
      }
#pragma unroll
      for (int mt = 0; mt < 4; ++mt)
#pragma unroll
        for (int nt = 0; nt < 4; ++nt)
          acc[mt][nt] = __builtin_amdgcn_mfma_f32_16x16x32_bf16(
              af[mt], bfr[nt], acc[mt][nt], 0, 0, 0);
    }
    __syncthreads();
  }
}

// ---------------------------------------------------------------------------
// PROJ_ALL (176 blocks, 256 thr): head proj + tail projs on compacted rows.
// ---------------------------------------------------------------------------
__global__ __launch_bounds__(256) void proj_all(
    const short* __restrict__ xb,
    const short* __restrict__ WpT0, const short* __restrict__ WpT1,
    const short* __restrict__ WpT2,
    short* __restrict__ P0b, short* __restrict__ P1c, short* __restrict__ P2c,
    const int* __restrict__ rows1, const int* __restrict__ rows2,
    const int* __restrict__ counts) {
  int b = blockIdx.x;
  const short* BT; short* C; int N, r0, c0, cnt;
  const int* rowlist = nullptr;
  if (b < 128) {
    BT = WpT0; C = P0b; N = 1024;
    c0 = (b & 7) * 128; r0 = (b >> 3) * 128; cnt = NROWS;
  } else if (b < 160) {
    b -= 128; BT = WpT1; C = P1c; N = 256;
    c0 = (b & 1) * 128; r0 = (b >> 1) * 128; rowlist = rows1; cnt = counts[1];
  } else {
    b -= 160; BT = WpT2; C = P2c; N = 64;
    c0 = 0; r0 = b * 128; rowlist = rows2; cnt = counts[2];
  }
  if (r0 >= cnt) return;

  __shared__ short As[128 * 64];
  __shared__ short Bs[128 * 64];
  const int tid = threadIdx.x;
  const int w = tid >> 6, lane = tid & 63;
  const int quad = lane >> 4, ln = lane & 15;
  const int wm = w >> 1, wn = w & 1;
  const int rsub = lane >> 3;
  const int kc = (lane & 7) ^ rsub;
  const int K = 1024;

  const short* aB[4]; const short* bB[4];
#pragma unroll
  for (int i = 0; i < 4; ++i) {
    const int sl = r0 + w * 32 + i * 8 + rsub;
    const int ar = rowlist ? rowlist[sl < cnt ? sl : cnt - 1] : sl;
    aB[i] = xb + (size_t)ar * K + kc * 8;
    bB[i] = BT + (size_t)(c0 + w * 32 + i * 8 + rsub) * K + kc * 8;
  }

  f32x4 acc[4][4];
  const f32x4 zero = {0.f, 0.f, 0.f, 0.f};
#pragma unroll
  for (int i = 0; i < 4; ++i)
#pragma unroll
    for (int j = 0; j < 4; ++j) acc[i][j] = zero;
  mfma_mainloop(aB, bB, As, Bs, acc, K, w, lane);
#pragma unroll
  for (int mt = 0; mt < 4; ++mt)
#pragma unroll
    for (int r = 0; r < 4; ++r) {
      const int grow = r0 + wm * 64 + mt * 16 + quad * 4 + r;
#pragma unroll
      for (int nt = 0; nt < 4; ++nt) {
        const int cg = c0 + wn * 64 + nt * 16 + ln;
        if (cg < N) C[(size_t)grow * N + cg] = f2bf(acc[mt][nt][r]);
      }
    }
}

// ---------------------------------------------------------------------------
// LOGIT_FUSED (2896 blocks x 512 thr, homogeneous 256x256 pipelined blocks):
//   blocks 0..319     head  (8 rb x 40 cb, XCD-partitioned cols, K=1024)
//   blocks 320..1263  tail1 (8 rb x 118 cb, K=256; early-return if r0>=cnt1)
//   blocks 1264..2895 tail2 (8 rb x 204 cb, K=64;  early-return if r0>=cnt2)
// Heads dispatched first (longest blocks) so tails pack the remaining CUs.
// ---------------------------------------------------------------------------
__global__ __launch_bounds__(512, 2) void logit_fused(
    const short* __restrict__ P0b, const short* __restrict__ WlT0,
    const float* __restrict__ bl0, float* __restrict__ psh,
    const short* __restrict__ P1c, const short* __restrict__ WlT1,
    const float* __restrict__ bl1, float* __restrict__ ps1,
    const short* __restrict__ P2c, const short* __restrict__ WlT2,
    const float* __restrict__ bl2, float* __restrict__ ps2,
    const int* __restrict__ counts) {
  __shared__ short lds[65536];   // 128 KiB (aliased for psE in the epilogue)
  const int tid = threadIdx.x;
  const int w = tid >> 6, lane = tid & 63;
  const int b = blockIdx.x;

  const short* A; const short* BT; const float* bias; float* ps;
  int K, NT, Ncols, nsplit, r0; size_t c0;
  if (b < 320) {                       // ---- head ----
    const int xcd = b & 7, j = b >> 3;
    const int cb = xcd * 5 + j % 5, rb = j / 5;
    r0 = rb * 256; c0 = (size_t)cb * 256;
    A = P0b; BT = WlT0; bias = bl0; ps = psh;
    K = 1024; NT = 16; Ncols = 10000; nsplit = 79;
  } else if (b < 1264) {               // ---- tail1 ----
    const int b1 = b - 320;
    const int rb = b1 / 118, cb = b1 % 118;
    r0 = rb * 256;
    if (r0 >= counts[1]) return;
    c0 = (size_t)cb * 256;
    A = P1c; BT = WlT1; bias = bl1; ps = ps1;
    K = 256; NT = 4; Ncols = 30000; nsplit = 235;
  } else {                             // ---- tail2 ----
    const int b2 = b - 1264;
    const int rb = b2 / 204, cb = b2 % 204;
    r0 = rb * 256;
    if (r0 >= counts[2]) return;
    c0 = (size_t)cb * 256;
    A = P2c; BT = WlT2; bias = bl2; ps = ps2;
    K = 64; NT = 1; Ncols = 52000; nsplit = 407;
  }

  f32x4 acc[2][2][4][2];
  const f32x4 zero = {0.f, 0.f, 0.f, 0.f};
#pragma unroll
  for (int qa = 0; qa < 2; ++qa)
#pragma unroll
    for (int qb = 0; qb < 2; ++qb)
#pragma unroll
      for (int mt = 0; mt < 4; ++mt)
#pragma unroll
        for (int nt = 0; nt < 2; ++nt) acc[qa][qb][mt][nt] = zero;

  gemm256(A, BT, K, NT, (size_t)r0, c0, lds, acc, w, lane);
  exp_epilogue(acc, bias, ps, c0, Ncols, nsplit, r0, lds, tid, w, lane);
}

// ---------------------------------------------------------------------------
// FINALIZE: one wave per row (unchanged).
// ---------------------------------------------------------------------------
__global__ __launch_bounds__(256) void finalize(
    const short* __restrict__ P0b, const short* __restrict__ P1c,
    const short* __restrict__ P2c,
    const short* __restrict__ WlT0, const float* __restrict__ bl0,
    const short* __restrict__ WlT1, const float* __restrict__ bl1,
    const short* __restrict__ WlT2, const float* __restrict__ bl2,
    const float* __restrict__ Wc, const float* __restrict__ bc,
    const int* __restrict__ y, const int* __restrict__ slot_of_row,
    const float* __restrict__ psh, const float* __restrict__ ps1,
    const float* __restrict__ ps2, float* __restrict__ out) {
  const int lane = threadIdx.x & 63;
  const int row = blockIdx.x * 4 + (threadIdx.x >> 6);

  float a0 = 0.f, a1 = 0.f;
  for (int k = lane; k < HID; k += 64) {
    const float p = bf2f(P0b[(size_t)row * HID + k]);
    a0 += p * Wc[2 * k];
    a1 += p * Wc[2 * k + 1];
  }
  a0 = wave_sum(a0);
  a1 = wave_sum(a1);
  const float cl0 = a0 + bc[0], cl1 = a1 + bc[1];

  float S = 0.f;
  for (int i = lane; i < 79; i += 64) S += psh[(size_t)row * 79 + i];
  S = wave_sum(S) + __expf(cl0) + __expf(cl1);
  const float lse = logf(S);

  const int yy = y[row];
  float nll;
  if (yy < 10000) {
    const short* pr = P0b + (size_t)row * 1024;
    const short* wr = WlT0 + (size_t)yy * 1024;
    float a = 0.f;
    for (int kk = lane * 4; kk < 1024; kk += 256) {
      const short4_t p = *(const short4_t*)(pr + kk);
      const short4_t wv = *(const short4_t*)(wr + kk);
      a += bf2f(p.x) * bf2f(wv.x) + bf2f(p.y) * bf2f(wv.y)
         + bf2f(p.z) * bf2f(wv.z) + bf2f(p.w) * bf2f(wv.w);
    }
    a = wave_sum(a);
    nll = -((a + bl0[yy]) - lse);
  } else if (yy < 20000) {
    const int t = yy - 10000;
    const int slot = slot_of_row[row];
    float S1 = 0.f;
    for (int i = lane; i < 235; i += 64) S1 += ps1[(size_t)slot * 235 + i];
    S1 = wave_sum(S1);
    const short* pr = P1c + (size_t)slot * 256;
    const short* wr = WlT1 + (size_t)t * 256;
    const int kk = lane * 4;
    const short4_t p = *(const short4_t*)(pr + kk);
    const short4_t wv = *(const short4_t*)(wr + kk);
    float a = bf2f(p.x) * bf2f(wv.x) + bf2f(p.y) * bf2f(wv.y)
            + bf2f(p.z) * bf2f(wv.z) + bf2f(p.w) * bf2f(wv.w);
    a = wave_sum(a);
    nll = -((cl1 - lse) + ((a + bl1[t]) - logf(S1)));
  } else {
    const int t = yy - 20000;
    const int slot = slot_of_row[row];
    float S2 = 0.f;
    for (int i = lane; i < 407; i += 64) S2 += ps2[(size_t)slot * 407 + i];
    S2 = wave_sum(S2);
    float a = 0.f;
    if (lane < 16) {
      const short* pr = P2c + (size_t)slot * 64;
      const short* wr = WlT2 + (size_t)t * 64;
      const int kk = lane * 4;
      const short4_t p = *(const short4_t*)(pr + kk);
      const short4_t wv = *(const short4_t*)(wr + kk);
      a = bf2f(p.x) * bf2f(wv.x) + bf2f(p.y) * bf2f(wv.y)
        + bf2f(p.z) * bf2f(wv.z) + bf2f(p.w) * bf2f(wv.w);
    }
    a = wave_sum(a);
    nll = -((cl0 - lse) + ((a + bl2[t]) - logf(S2)));
  }
  if (lane == 0) out[row] = nll;
}

// ---------------------------------------------------------------------------
extern "C" void kernel_launch(void* const* d_in, const int* in_sizes, int n_in,
                              void* d_out, int out_size, void* d_ws, size_t ws_size,
                              hipStream_t stream) {
  const float* x   = (const float*)d_in[0];
  const int*   y   = (const int*)d_in[1];
  const float* Wp0 = (const float*)d_in[2];
  const float* Wp1 = (const float*)d_in[3];
  const float* Wp2 = (const float*)d_in[4];
  const float* Wl0 = (const float*)d_in[5];
  const float* bl0 = (const float*)d_in[6];
  const float* Wl1 = (const float*)d_in[7];
  const float* bl1 = (const float*)d_in[8];
  const float* Wl2 = (const float*)d_in[9];
  const float* bl2 = (const float*)d_in[10];
  const float* Wc  = (const float*)d_in[11];
  const float* bc  = (const float*)d_in[12];
  float* out = (float*)d_out;

  float* fws = (float*)d_ws;
  float* psh = fws; fws += (size_t)NROWS * 79;
  float* ps1 = fws; fws += (size_t)NROWS * 235;
  float* ps2 = fws; fws += (size_t)NROWS * 407;
  int* iws = (int*)fws;
  int* counts      = iws; iws += 4;
  int* slot_of_row = iws; iws += NROWS;
  int* rows1       = iws; iws += NROWS;
  int* rows2       = iws; iws += NROWS;
  short* sp = (short*)iws;
  short* xb   = sp; sp += (size_t)NROWS * 1024;
  short* P0b  = sp; sp += (size_t)NROWS * 1024;
  short* P1c  = sp; sp += (size_t)NROWS * 256;
  short* P2c  = sp; sp += (size_t)NROWS * 64;
  short* WpT0 = sp; sp += (size_t)1024 * 1024;
  short* WpT1 = sp; sp += (size_t)256 * 1024;
  short* WpT2 = sp; sp += (size_t)128 * 1024;
  short* WlT0 = sp; sp += (size_t)10240 * 1024;
  short* WlT1 = sp; sp += (size_t)30208 * 256;
  short* WlT2 = sp; sp += (size_t)52224 * 64;

  dim3 blk(256);
  prep<<<dim3(24513), blk, 0, stream>>>(x, y, Wp0, Wp1, Wp2, Wl0, Wl1, Wl2,
                                        xb, counts, slot_of_row, rows1, rows2,
                                        WpT0, WpT1, WpT2, WlT0, WlT1, WlT2);
  proj_all<<<dim3(176), blk, 0, stream>>>(xb, WpT0, WpT1, WpT2, P0b, P1c, P2c,
                                          rows1, rows2, counts);
  logit_fused<<<dim3(2896), dim3(512), 0, stream>>>(
      P0b, WlT0, bl0, psh, P1c, WlT1, bl1, ps1, P2c, WlT2, bl2, ps2, counts);
  finalize<<<dim3(NROWS / 4), blk, 0, stream>>>(
      P0b, P1c, P2c, WlT0, bl0, WlT1, bl1, WlT2, bl2, Wc, bc, y, slot_of_row,
      psh, ps1, ps2, out);
}